// Round 8
// baseline (186.195 us; speedup 1.0000x reference)
//
#include <hip/hip_runtime.h>
#include <cstdint>
#include <cstddef>

#define B_    2048
#define L_    13
#define H_    768
#define NROW  (B_ * L_)          // 26624 flattened hidden rows
#define RTEMP 20.0f              // 1 / 0.05
#define NT    24                 // K tiles: 768 / 32
#define RS    1536               // global row stride bytes (H_ * 2)
#define SLOT  32768              // LDS slot: A 16KB (256 rows) + B 16KB (256 rows)
#define NSLOT 3

typedef short bf16x8 __attribute__((ext_vector_type(8)));
typedef float f32x4  __attribute__((ext_vector_type(4)));

static __device__ __forceinline__ unsigned short f2bf(float f) {
  union { float f; unsigned int i; } v; v.f = f;
  unsigned int r = v.i + 0x7fffu + ((v.i >> 16) & 1u);   // RNE
  return (unsigned short)(r >> 16);
}
static __device__ __forceinline__ unsigned int pack2(float a, float b) {
  return ((unsigned int)f2bf(b) << 16) | (unsigned int)f2bf(a);
}

__device__ __forceinline__ void llds16(const void* g, void* l) {
  __builtin_amdgcn_global_load_lds(
      (const __attribute__((address_space(1))) void*)g,
      (__attribute__((address_space(3))) void*)l, 16, 0, 0);
}

#define BAR do { asm volatile("" ::: "memory");            \
    __builtin_amdgcn_s_barrier();                          \
    asm volatile("" ::: "memory"); } while (0)
#define WAIT_LGKM do { asm volatile("s_waitcnt lgkmcnt(0)" ::: "memory"); \
    __builtin_amdgcn_sched_barrier(0); } while (0)

// ---------------------------------------------------------------------------
// Kernel 1: L2-normalize rows, cast to bf16. One wave per row, 4 rows/block.
// ---------------------------------------------------------------------------
__global__ __launch_bounds__(256) void k_normalize(
    const float* __restrict__ cls, const float* __restrict__ hidden,
    unsigned short* __restrict__ cn, unsigned short* __restrict__ hn)
{
  const int wid = threadIdx.x >> 6, lane = threadIdx.x & 63;
  const int row = blockIdx.x * 4 + wid;
  const float4* src; unsigned short* dst;
  if (row < B_) { src = (const float4*)(cls + (size_t)row * H_);          dst = cn + (size_t)row * H_; }
  else          { src = (const float4*)(hidden + (size_t)(row - B_) * H_); dst = hn + (size_t)(row - B_) * H_; }

  float4 x0 = src[lane], x1 = src[lane + 64], x2 = src[lane + 128];
  float ss = x0.x*x0.x + x0.y*x0.y + x0.z*x0.z + x0.w*x0.w
           + x1.x*x1.x + x1.y*x1.y + x1.z*x1.z + x1.w*x1.w
           + x2.x*x2.x + x2.y*x2.y + x2.z*x2.z + x2.w*x2.w;
#pragma unroll
  for (int m = 1; m < 64; m <<= 1) ss += __shfl_xor(ss, m);
  const float sc = 1.0f / fmaxf(sqrtf(ss), 1e-8f);

  uint2* d2 = (uint2*)dst;
  uint2 p;
  p.x = pack2(x0.x * sc, x0.y * sc); p.y = pack2(x0.z * sc, x0.w * sc); d2[lane]       = p;
  p.x = pack2(x1.x * sc, x1.y * sc); p.y = pack2(x1.z * sc, x1.w * sc); d2[lane + 64]  = p;
  p.x = pack2(x2.x * sc, x2.y * sc); p.y = pack2(x2.z * sc, x2.w * sc); d2[lane + 128] = p;
}

// ---------------------------------------------------------------------------
// Kernel 2: m201-template port. BM=BN=256, BK=32, 8 waves (2M x 4N), 512 thr,
// wave tile 128x64, 1 block/CU. 3-slot LDS ring (3 x 32KB). Per K-tile two
// 16-MFMA phases, each {ds_read || 2 global_load_lds -> BAR -> lgkmcnt(0)
// -> setprio+MFMA+setprio -> BAR}; stage tile t+2 during t; ONE counted
// vmcnt(4) per tile before the tile-end barrier (t+1 landed collectively,
// t+2's 4 chunks stay in flight; never drains until the 2-tile tail).
// Paired-row XOR swizzle (0 conflicts, R2-R7) via inverse-swizzled global
// source. M-inner XCD map (FETCH ~44MB, R6-validated). Fused epilogue.
// ---------------------------------------------------------------------------
__global__ __launch_bounds__(512, 2) void k_gemm(
    const unsigned short* __restrict__ cn,
    const unsigned short* __restrict__ hn,
    float* __restrict__ S_all,
    float* __restrict__ alignedD)
{
  __shared__ __align__(16) char lds[NSLOT * SLOT];   // 96KB

  const int tid  = threadIdx.x;
  const int lane = tid & 63;
  const int wid  = tid >> 6;           // 0..7
  const int wm   = wid >> 2;           // 0..1  (M half: 128 rows)
  const int wn   = wid & 3;            // 0..3  (N quarter: 64 cols)
  const int fr   = lane & 15, q = lane >> 4, fr2 = (lane & 15) >> 1;

  // 832 blocks = 8 XCD x (13 N-panels x 8 M-panels), M-inner: B-panel
  // (393KB) L2-hot across its 8 M-blocks; cn (3.1MB) L2-resident per XCD.
  const int wg   = blockIdx.x;
  const int xcd  = wg & 7;
  const int idx  = wg >> 3;            // 0..103
  const int brow = (idx & 7) * 256;
  const int bcol = (xcd * 13 + (idx >> 3)) * 256;

  // --- staging map (linear LDS dest, inverse-swizzled global source) ------
  // 512 threads cover one 8KB chunk = 128 rows x 64B (paired-row lines).
  const int slot_un = (tid & 7) ^ ((tid >> 3) & 7);
  const int srow = 2 * (tid >> 3) + (slot_un >> 2);   // 0..127
  const int scb  = (slot_un & 3) << 4;
  const char* gA = (const char*)cn + (size_t)(brow + srow) * RS + scb;
  const char* gB = (const char*)hn + (size_t)(bcol + srow) * RS + scb;

  // slot layout: A rows 0..127 at +0, 128..255 at +8192; B rows 0..127 at
  // +16384, 128..255 at +24576.
#define STAGE_A(ss, t) do { char* d_ = lds + (ss) + tid * 16;   \
    const char* a_ = gA + (t) * 64;                             \
    llds16(a_,            d_);                                  \
    llds16(a_ + 128 * RS, d_ + 8192); } while (0)
#define STAGE_B(ss, t) do { char* d_ = lds + (ss) + 16384 + tid * 16; \
    const char* b_ = gB + (t) * 64;                             \
    llds16(b_,            d_);                                  \
    llds16(b_ + 128 * RS, d_ + 8192); } while (0)

  // --- fragment read offsets (paired-row XOR swizzle) ---------------------
  const int swz  = ((((fr & 1) << 2) | q) ^ (fr2 & 7)) << 4;
  const int offA = wm * 8192 + fr2 * 128 + swz;             // + mi*1024, mi<8
  const int offB = 16384 + wn * 4096 + fr2 * 128 + swz;     // + ni*1024, ni<4

  f32x4 acc[8][4] = {};

  // prologue: tiles 0,1 staged (8 chunks); vmcnt(4)+BAR -> tile 0 landed
  STAGE_A(0, 0); STAGE_B(0, 0);
  STAGE_A(SLOT, 1); STAGE_B(SLOT, 1);
  asm volatile("s_waitcnt vmcnt(4)" ::: "memory");
  BAR;

  int baseR = 0, baseS = 2 * SLOT;
  for (int t = 0; t < NT; ++t) {
    const char* bb = lds + baseR;
    bf16x8 a0[4], a1[4], bv[4];

    // ===== phase 0: acc rows mi 0..3, all B frags; stage A of t+2 =========
#pragma unroll
    for (int i = 0; i < 4; ++i) a0[i] = *(const bf16x8*)(bb + offA + i * 1024);
#pragma unroll
    for (int i = 0; i < 4; ++i) bv[i] = *(const bf16x8*)(bb + offB + i * 1024);
    if (t + 2 < NT) STAGE_A(baseS, t + 2);
    BAR;
    WAIT_LGKM;
    __builtin_amdgcn_s_setprio(1);
#pragma unroll
    for (int mi = 0; mi < 4; ++mi)
#pragma unroll
      for (int ni = 0; ni < 4; ++ni)
        acc[mi][ni] = __builtin_amdgcn_mfma_f32_16x16x32_bf16(
            a0[mi], bv[ni], acc[mi][ni], 0, 0, 0);
    __builtin_amdgcn_s_setprio(0);
    BAR;

    // ===== phase 1: acc rows mi 4..7 (B frags held); stage B of t+2 =======
#pragma unroll
    for (int i = 0; i < 4; ++i) a1[i] = *(const bf16x8*)(bb + offA + 4096 + i * 1024);
    if (t + 2 < NT) STAGE_B(baseS, t + 2);
    BAR;
    WAIT_LGKM;
    __builtin_amdgcn_s_setprio(1);
#pragma unroll
    for (int mi = 0; mi < 4; ++mi)
#pragma unroll
      for (int ni = 0; ni < 4; ++ni)
        acc[mi + 4][ni] = __builtin_amdgcn_mfma_f32_16x16x32_bf16(
            a1[mi], bv[ni], acc[mi + 4][ni], 0, 0, 0);
    __builtin_amdgcn_s_setprio(0);

    // tile-end collective guarantee: t+1's 4 chunks landed, t+2's 4 fly on
    if (t + 2 < NT)      { asm volatile("s_waitcnt vmcnt(4)" ::: "memory"); }
    else if (t + 1 < NT) { asm volatile("s_waitcnt vmcnt(0)" ::: "memory"); }
    BAR;

    baseR += SLOT; if (baseR >= NSLOT * SLOT) baseR = 0;
    baseS += SLOT; if (baseS >= NSLOT * SLOT) baseS = 0;
  }
#undef STAGE_A
#undef STAGE_B

  // --- epilogue: row = brow+wm*128+mi*16+q*4+j, col = bcol+wn*64+ni*16+fr -
  const int rowb = brow + wm * 128;
  const int colb = bcol + wn * 64;
#pragma unroll
  for (int mi = 0; mi < 8; ++mi) {
#pragma unroll
    for (int j = 0; j < 4; ++j) {
      const int grow = rowb + mi * 16 + q * 4 + j;
      float v = 0.f;
#pragma unroll
      for (int ni = 0; ni < 4; ++ni) {
        const int gcol = colb + ni * 16 + fr;
        const float a = acc[mi][ni][j];
        if ((unsigned)(gcol - grow * 13) < 13u) alignedD[gcol] = a;  // raw dot
        v += ((gcol & 2047) == grow) ? 0.f : __expf(RTEMP * a);     // masked sum
      }
      v += __shfl_xor(v, 1); v += __shfl_xor(v, 2);
      v += __shfl_xor(v, 4); v += __shfl_xor(v, 8);
      if (fr == 0) atomicAdd(&S_all[grow], v);
    }
  }
}

// ---------------------------------------------------------------------------
// Kernel 3: per row i: loss_i = sum_l [ log(exp(20 d_l) + s_i) - 20 d_l ].
// ---------------------------------------------------------------------------
__global__ __launch_bounds__(256) void k_finalize(
    const float* __restrict__ S_all, const float* __restrict__ alignedD,
    float* __restrict__ out)
{
  const int i = blockIdx.x * 256 + threadIdx.x;
  const int lane = threadIdx.x & 63, wid = threadIdx.x >> 6;
  const float s = S_all[i];
  float accv = 0.f;
#pragma unroll
  for (int l = 0; l < L_; l++) {
    const float d = RTEMP * alignedD[i * L_ + l];
    accv += logf(__expf(d) + s) - d;
  }
#pragma unroll
  for (int m = 1; m < 64; m <<= 1) accv += __shfl_xor(accv, m);
  __shared__ float wsum[4];
  if (lane == 0) wsum[wid] = accv;
  __syncthreads();
  if (threadIdx.x == 0)
    atomicAdd(out, (wsum[0] + wsum[1] + wsum[2] + wsum[3]) * (1.0f / (float)(B_ * L_)));
}

// ---------------------------------------------------------------------------
extern "C" void kernel_launch(void* const* d_in, const int* in_sizes, int n_in,
                              void* d_out, int out_size, void* d_ws, size_t ws_size,
                              hipStream_t stream) {
  const float* cls    = (const float*)d_in[0];
  const float* hidden = (const float*)d_in[1];
  float* out = (float*)d_out;

  // ws: hn bf16 (40,894,464) | cn bf16 (3,145,728) | S_all (8,192) | alignedD (106,496)
  char* ws = (char*)d_ws;
  unsigned short* hn = (unsigned short*)ws;
  unsigned short* cn = (unsigned short*)(ws + (size_t)NROW * H_ * 2);
  float* S_all    = (float*)(ws + (size_t)NROW * H_ * 2 + (size_t)B_ * H_ * 2);
  float* alignedD = (float*)(ws + (size_t)NROW * H_ * 2 + (size_t)B_ * H_ * 2 + B_ * sizeof(float));

  hipMemsetAsync(S_all, 0, B_ * sizeof(float), stream);
  hipMemsetAsync(out, 0, sizeof(float), stream);

  k_normalize<<<(B_ + NROW) / 4, 256, 0, stream>>>(cls, hidden, cn, hn);
  k_gemm<<<8 * 104, 512, 0, stream>>>(cn, hn, S_all, alignedD);
  k_finalize<<<B_ / 256, 256, 0, stream>>>(S_all, alignedD, out);
}

// Round 9
// 144.027 us; speedup vs baseline: 1.2928x; 1.2928x over previous
//
#include <hip/hip_runtime.h>
#include <cstdint>
#include <cstddef>

#define B_    2048
#define L_    13
#define H_    768
#define NROW  (B_ * L_)          // 26624 flattened hidden rows
#define RTEMP 20.0f              // 1 / 0.05
#define NT    24                 // K tiles: 768 / 32
#define RS    1536               // global row stride bytes (H_ * 2)
#define NTILE 3328               // 16 M-panels x 208 N-panels (128x128 tiles)
#define GRID  1024               // persistent blocks: 4 per CU

typedef short bf16x8 __attribute__((ext_vector_type(8)));
typedef float f32x4  __attribute__((ext_vector_type(4)));

static __device__ __forceinline__ unsigned short f2bf(float f) {
  union { float f; unsigned int i; } v; v.f = f;
  unsigned int r = v.i + 0x7fffu + ((v.i >> 16) & 1u);   // RNE
  return (unsigned short)(r >> 16);
}
static __device__ __forceinline__ unsigned int pack2(float a, float b) {
  return ((unsigned int)f2bf(b) << 16) | (unsigned int)f2bf(a);
}

__device__ __forceinline__ void llds16(const void* g, void* l) {
  __builtin_amdgcn_global_load_lds(
      (const __attribute__((address_space(1))) void*)g,
      (__attribute__((address_space(3))) void*)l, 16, 0, 0);
}

#define BAR do { asm volatile("" ::: "memory");            \
    __builtin_amdgcn_s_barrier();                          \
    asm volatile("" ::: "memory"); } while (0)

// ---------------------------------------------------------------------------
// Kernel 1: L2-normalize rows, cast to bf16. One wave per row, 4 rows/block.
// ---------------------------------------------------------------------------
__global__ __launch_bounds__(256) void k_normalize(
    const float* __restrict__ cls, const float* __restrict__ hidden,
    unsigned short* __restrict__ cn, unsigned short* __restrict__ hn)
{
  const int wid = threadIdx.x >> 6, lane = threadIdx.x & 63;
  const int row = blockIdx.x * 4 + wid;
  const float4* src; unsigned short* dst;
  if (row < B_) { src = (const float4*)(cls + (size_t)row * H_);          dst = cn + (size_t)row * H_; }
  else          { src = (const float4*)(hidden + (size_t)(row - B_) * H_); dst = hn + (size_t)(row - B_) * H_; }

  float4 x0 = src[lane], x1 = src[lane + 64], x2 = src[lane + 128];
  float ss = x0.x*x0.x + x0.y*x0.y + x0.z*x0.z + x0.w*x0.w
           + x1.x*x1.x + x1.y*x1.y + x1.z*x1.z + x1.w*x1.w
           + x2.x*x2.x + x2.y*x2.y + x2.z*x2.z + x2.w*x2.w;
#pragma unroll
  for (int m = 1; m < 64; m <<= 1) ss += __shfl_xor(ss, m);
  const float sc = 1.0f / fmaxf(sqrtf(ss), 1e-8f);

  uint2* d2 = (uint2*)dst;
  uint2 p;
  p.x = pack2(x0.x * sc, x0.y * sc); p.y = pack2(x0.z * sc, x0.w * sc); d2[lane]       = p;
  p.x = pack2(x1.x * sc, x1.y * sc); p.y = pack2(x1.z * sc, x1.w * sc); d2[lane + 64]  = p;
  p.x = pack2(x2.x * sc, x2.y * sc); p.y = pack2(x2.z * sc, x2.w * sc); d2[lane + 128] = p;
}

// ---------------------------------------------------------------------------
// Kernel 2: persistent 4-blocks/CU GEMM. 128x128 tile, BK=32, 4 waves (2x2),
// wave tile 64x64 -> acc 64 regs, total ~120 -> launch_bounds(256,4) caps at
// 128 regs -> 16 waves/CU = 4 INDEPENDENT blocks per SIMD (asynchrony covers
// barrier/drain stalls; R5->R6 showed +31% from 1->2 groups). 2-slot LDS
// (32KB). Per tile: stage t+1 at top, ds_read+MFMA, vmcnt(0)+BAR. Persistent:
// each block walks tiles wg, wg+1024, ... (same XCD, same A-rows -> L2-hot);
// next tile's k0 staged under the epilogue (tail 25% -> ~8%).
// Paired-row XOR swizzle (0 conflicts R2-R8). Fused exp/mask/row-sum epilogue.
// ---------------------------------------------------------------------------
__global__ __launch_bounds__(256, 4) void k_gemm(
    const unsigned short* __restrict__ cn,
    const unsigned short* __restrict__ hn,
    float* __restrict__ S_all,
    float* __restrict__ alignedD)
{
  __shared__ __align__(16) char lds[32768];   // 2 slots x (A 8KB | B 8KB)

  const int tid  = threadIdx.x;
  const int lane = tid & 63;
  const int wid  = tid >> 6;           // 0..3
  const int wm   = wid >> 1;           // 0..1  (M half: 64 rows)
  const int wn   = wid & 1;            // 0..1  (N half: 64 cols)
  const int fr   = lane & 15, q = lane >> 4, fr2 = (lane & 15) >> 1;

  // fragment read offsets (paired-row XOR swizzle, validated R2-R8)
  const int swz  = ((((fr & 1) << 2) | q) ^ (fr2 & 7)) << 4;
  const int offA = wm * 4096 + fr2 * 128 + swz;            // + mi*1024, mi<4
  const int offB = 8192 + wn * 4096 + fr2 * 128 + swz;     // + ni*1024, ni<4

  // staging map (linear LDS dest, inverse-swizzled global source)
  const int slot_un = (tid & 7) ^ ((tid >> 3) & 7);
  const int srow = 2 * (tid >> 3) + (slot_un >> 2);   // 0..63
  const int scb  = (slot_un & 3) << 4;
  char* ldst = lds + tid * 16;

  // tile decode: 3328 = 8 XCD x (26 N x 16 M), M-inner. tile+1024 keeps the
  // same xcd (1024%8==0) AND the same brow ((idx+128)&15 == idx&15).
#define DECODE(tile, ga, gb, br, bc) do {                         \
    const int xcd_ = (tile) & 7, idx_ = (tile) >> 3;              \
    (br) = (idx_ & 15) << 7;                                      \
    (bc) = (xcd_ * 26 + (idx_ >> 4)) << 7;                        \
    (ga) = (const char*)cn + (size_t)((br) + srow) * RS + scb;    \
    (gb) = (const char*)hn + (size_t)((bc) + srow) * RS + scb;    \
  } while (0)

  // A rows 0..63 at +0, 64..127 at +4096; B rows likewise at +8192/+12288.
#define STAGE(sb, ga, gb, t) do {                                 \
    char* d_ = ldst + (sb);                                       \
    const char* a_ = (ga) + (t) * 64;                             \
    llds16(a_,           d_);                                     \
    llds16(a_ + 64 * RS, d_ + 4096);                              \
    const char* b_ = (gb) + (t) * 64;                             \
    llds16(b_,           d_ + 8192);                              \
    llds16(b_ + 64 * RS, d_ + 12288);                             \
  } while (0)

  const char *gA, *gB; int brow, bcol;
  DECODE(blockIdx.x, gA, gB, brow, bcol);
  STAGE(0, gA, gB, 0);                       // first tile's k0

  for (int tile = blockIdx.x; tile < NTILE; tile += GRID) {
    asm volatile("s_waitcnt vmcnt(0)" ::: "memory");   // k0 landed
    BAR;

    const bool hasnext = (tile + GRID) < NTILE;
    const char *gA2 = gA, *gB2 = gB; int brow2 = brow, bcol2 = bcol;

    f32x4 acc[4][4] = {};

    for (int t = 0; t < NT; ++t) {
      // stage next K-chunk into the other slot (WAR-safe behind last BAR);
      // at t==NT-1 stage the NEXT TILE's k0 -> latency hides under epilogue
      if (t + 1 < NT) {
        STAGE(((t + 1) & 1) * 16384, gA, gB, t + 1);
      } else if (hasnext) {
        DECODE(tile + GRID, gA2, gB2, brow2, bcol2);
        STAGE(0, gA2, gB2, 0);
      }

      const char* bb = lds + (t & 1) * 16384;
      bf16x8 af[4], bf[4];
#pragma unroll
      for (int i = 0; i < 4; ++i) af[i] = *(const bf16x8*)(bb + offA + i * 1024);
#pragma unroll
      for (int i = 0; i < 4; ++i) bf[i] = *(const bf16x8*)(bb + offB + i * 1024);

      __builtin_amdgcn_s_setprio(1);
#pragma unroll
      for (int mi = 0; mi < 4; ++mi)
#pragma unroll
        for (int ni = 0; ni < 4; ++ni)
          acc[mi][ni] = __builtin_amdgcn_mfma_f32_16x16x32_bf16(
              af[mi], bf[ni], acc[mi][ni], 0, 0, 0);
      __builtin_amdgcn_s_setprio(0);

      if (t + 1 < NT) {   // t+1's 4 loads had the ds_read+MFMA span to land
        asm volatile("s_waitcnt vmcnt(0)" ::: "memory");
        BAR;
      }
      // t==NT-1: fall through; next-tile k0 stays in flight through epilogue
    }

    // epilogue: row = brow+wm*64+mi*16+q*4+j, col = bcol+wn*64+ni*16+fr
    const int rowb = brow + wm * 64;
    const int colb = bcol + wn * 64;
#pragma unroll
    for (int mi = 0; mi < 4; ++mi) {
#pragma unroll
      for (int j = 0; j < 4; ++j) {
        const int grow = rowb + mi * 16 + q * 4 + j;
        float v = 0.f;
#pragma unroll
        for (int ni = 0; ni < 4; ++ni) {
          const int gcol = colb + ni * 16 + fr;
          const float a = acc[mi][ni][j];
          if ((unsigned)(gcol - grow * 13) < 13u) alignedD[gcol] = a;  // raw dot
          v += ((gcol & 2047) == grow) ? 0.f : __expf(RTEMP * a);     // masked sum
        }
        v += __shfl_xor(v, 1); v += __shfl_xor(v, 2);
        v += __shfl_xor(v, 4); v += __shfl_xor(v, 8);
        if (fr == 0) atomicAdd(&S_all[grow], v);
      }
    }

    gA = gA2; gB = gB2; brow = brow2; bcol = bcol2;
  }
#undef STAGE
#undef DECODE
}

// ---------------------------------------------------------------------------
// Kernel 3: per row i: loss_i = sum_l [ log(exp(20 d_l) + s_i) - 20 d_l ].
// ---------------------------------------------------------------------------
__global__ __launch_bounds__(256) void k_finalize(
    const float* __restrict__ S_all, const float* __restrict__ alignedD,
    float* __restrict__ out)
{
  const int i = blockIdx.x * 256 + threadIdx.x;
  const int lane = threadIdx.x & 63, wid = threadIdx.x >> 6;
  const float s = S_all[i];
  float accv = 0.f;
#pragma unroll
  for (int l = 0; l < L_; l++) {
    const float d = RTEMP * alignedD[i * L_ + l];
    accv += logf(__expf(d) + s) - d;
  }
#pragma unroll
  for (int m = 1; m < 64; m <<= 1) accv += __shfl_xor(accv, m);
  __shared__ float wsum[4];
  if (lane == 0) wsum[wid] = accv;
  __syncthreads();
  if (threadIdx.x == 0)
    atomicAdd(out, (wsum[0] + wsum[1] + wsum[2] + wsum[3]) * (1.0f / (float)(B_ * L_)));
}

// ---------------------------------------------------------------------------
extern "C" void kernel_launch(void* const* d_in, const int* in_sizes, int n_in,
                              void* d_out, int out_size, void* d_ws, size_t ws_size,
                              hipStream_t stream) {
  const float* cls    = (const float*)d_in[0];
  const float* hidden = (const float*)d_in[1];
  float* out = (float*)d_out;

  // ws: hn bf16 (40,894,464) | cn bf16 (3,145,728) | S_all (8,192) | alignedD (106,496)
  char* ws = (char*)d_ws;
  unsigned short* hn = (unsigned short*)ws;
  unsigned short* cn = (unsigned short*)(ws + (size_t)NROW * H_ * 2);
  float* S_all    = (float*)(ws + (size_t)NROW * H_ * 2 + (size_t)B_ * H_ * 2);
  float* alignedD = (float*)(ws + (size_t)NROW * H_ * 2 + (size_t)B_ * H_ * 2 + B_ * sizeof(float));

  hipMemsetAsync(S_all, 0, B_ * sizeof(float), stream);
  hipMemsetAsync(out, 0, sizeof(float), stream);

  k_normalize<<<(B_ + NROW) / 4, 256, 0, stream>>>(cls, hidden, cn, hn);
  k_gemm<<<GRID, 256, 0, stream>>>(cn, hn, S_all, alignedD);
  k_finalize<<<B_ / 256, 256, 0, stream>>>(S_all, alignedD, out);
}

// Round 10
// 115.223 us; speedup vs baseline: 1.6160x; 1.2500x over previous
//
#include <hip/hip_runtime.h>
#include <cstdint>
#include <cstddef>

#define B_    2048
#define L_    13
#define H_    768
#define NROW  (B_ * L_)          // 26624 flattened hidden rows
#define RTEMP 20.0f              // 1 / 0.05
#define NT    12                 // K tiles: 768 / 64
#define RS    768                // fp8 row stride bytes
#define NTILE 3328               // 16 M-panels x 208 N-panels (128x128 tiles)
#define GRID  1024               // persistent blocks: 4 per CU

typedef float f32x4 __attribute__((ext_vector_type(4)));
typedef long  i64x2 __attribute__((ext_vector_type(2)));

// ---- f32 -> OCP e4m3fn, RNE, saturating (no NaN/Inf inputs here) ----------
static __device__ __forceinline__ unsigned int f2e4m3(float f) {
  unsigned int u = __float_as_uint(f);
  unsigned int s = (u >> 24) & 0x80u;
  unsigned int ua = u & 0x7fffffffu;
  if (ua >= 0x43e80000u) return s | 0x7eu;          // >= 464 -> saturate 448
  if (ua < 0x3c800000u) {                           // < 2^-6: subnormal range
    int m = (int)rintf(__uint_as_float(ua) * 512.0f);   // 0..8 (8 -> 0x08 = 2^-6)
    return s | (unsigned int)m;
  }
  unsigned int lsb = (ua >> 20) & 1u;
  unsigned int r = ua + 0x7ffffu + lsb;             // RNE to 3 mantissa bits
  int Ee = (int)((r >> 23) & 0xffu) - 127;          // carry handled naturally
  unsigned int mant = (r >> 20) & 7u;
  return s | (unsigned int)(((Ee + 7) << 3) | mant);
}

__device__ __forceinline__ void llds16(const void* g, void* l) {
  __builtin_amdgcn_global_load_lds(
      (const __attribute__((address_space(1))) void*)g,
      (__attribute__((address_space(3))) void*)l, 16, 0, 0);
}

#define BAR do { asm volatile("" ::: "memory");            \
    __builtin_amdgcn_s_barrier();                          \
    asm volatile("" ::: "memory"); } while (0)

// Interleaved fp8 row layout (per 64-B K-chunk): slot q (16B) holds
// k[q*8..q*8+7] then k[32+q*8..32+q*8+7] -> a b128 LDS read yields both
// K32-halves of a 16x16x32 fragment. 4-aligned k -> byte offset:
#define OFF8(k) ((((k) >> 6) << 6) + (((((k) & 31) >> 3)) << 4) + ((((k) & 32) ? 8 : 0)) + ((k) & 7))

// ---------------------------------------------------------------------------
// Kernel 1: L2-normalize rows (f32 math), quantize to e4m3, store in the
// interleaved chunk layout. One wave per row, 4 rows/block.
// ---------------------------------------------------------------------------
__global__ __launch_bounds__(256) void k_normalize(
    const float* __restrict__ cls, const float* __restrict__ hidden,
    unsigned char* __restrict__ cn8, unsigned char* __restrict__ hn8)
{
  const int wid = threadIdx.x >> 6, lane = threadIdx.x & 63;
  const int row = blockIdx.x * 4 + wid;
  const float4* src; unsigned char* dst;
  if (row < B_) { src = (const float4*)(cls + (size_t)row * H_);           dst = cn8 + (size_t)row * RS; }
  else          { src = (const float4*)(hidden + (size_t)(row - B_) * H_); dst = hn8 + (size_t)(row - B_) * RS; }

  float4 x0 = src[lane], x1 = src[lane + 64], x2 = src[lane + 128];
  float ss = x0.x*x0.x + x0.y*x0.y + x0.z*x0.z + x0.w*x0.w
           + x1.x*x1.x + x1.y*x1.y + x1.z*x1.z + x1.w*x1.w
           + x2.x*x2.x + x2.y*x2.y + x2.z*x2.z + x2.w*x2.w;
#pragma unroll
  for (int m = 1; m < 64; m <<= 1) ss += __shfl_xor(ss, m);
  const float sc = 1.0f / fmaxf(sqrtf(ss), 1e-8f);

  const int k = lane * 4;
  unsigned int p0 = f2e4m3(x0.x*sc) | (f2e4m3(x0.y*sc) << 8) | (f2e4m3(x0.z*sc) << 16) | (f2e4m3(x0.w*sc) << 24);
  unsigned int p1 = f2e4m3(x1.x*sc) | (f2e4m3(x1.y*sc) << 8) | (f2e4m3(x1.z*sc) << 16) | (f2e4m3(x1.w*sc) << 24);
  unsigned int p2 = f2e4m3(x2.x*sc) | (f2e4m3(x2.y*sc) << 8) | (f2e4m3(x2.z*sc) << 16) | (f2e4m3(x2.w*sc) << 24);
  *(unsigned int*)(dst + OFF8(k))       = p0;
  *(unsigned int*)(dst + OFF8(k + 256)) = p1;
  *(unsigned int*)(dst + OFF8(k + 512)) = p2;
}

// ---------------------------------------------------------------------------
// Kernel 2: fp8 persistent GEMM. R9 skeleton (4 blocks/CU, 128x128 tile,
// 4 waves 2x2, wave tile 64x64, 2-slot LDS dbuf 32KB, stage t+1 at top,
// vmcnt(0)+BAR per K-tile, stage-next-tile-under-epilogue, M-inner XCD map)
// at HALF the LDS bytes/FLOP: e4m3 operands, BK=64 (12 K-iters),
// mfma_f32_16x16x32_fp8_fp8, b128 frag reads = both K32 halves.
// Paired-row XOR swizzle formula identical to the R2-R9-validated one.
// ---------------------------------------------------------------------------
__global__ __launch_bounds__(256, 4) void k_gemm(
    const unsigned char* __restrict__ cn8,
    const unsigned char* __restrict__ hn8,
    float* __restrict__ S_all,
    float* __restrict__ alignedD)
{
  __shared__ __align__(16) char lds[32768];   // 2 slots x (A 8KB | B 8KB)

  const int tid  = threadIdx.x;
  const int lane = tid & 63;
  const int wid  = tid >> 6;           // 0..3
  const int wm   = wid >> 1;           // 0..1  (M half: 64 rows)
  const int wn   = wid & 1;            // 0..1  (N half: 64 cols)
  const int fr   = lane & 15, q = lane >> 4, fr2 = (lane & 15) >> 1;

  // fragment read offsets: line = (64-row pair) index, slot XOR-swizzled.
  const int swz  = ((q | ((fr & 1) << 2)) ^ (fr2 & 7)) << 4;
  const int offA = wm * 4096 + fr2 * 128 + swz;            // + mi*1024, mi<4
  const int offB = 8192 + wn * 4096 + fr2 * 128 + swz;     // + ni*1024, ni<4

  // staging map (linear LDS dest, inverse-swizzled global source)
  const int slot_un = (tid & 7) ^ ((tid >> 3) & 7);
  const int srow = 2 * (tid >> 3) + (slot_un >> 2);   // 0..63
  const int scb  = (slot_un & 3) << 4;
  char* ldst = lds + tid * 16;

  // tile decode: 3328 = 8 XCD x (26 N x 16 M), M-inner; tile+1024 keeps xcd+brow
#define DECODE(tile, ga, gb, br, bc) do {                         \
    const int xcd_ = (tile) & 7, idx_ = (tile) >> 3;              \
    (br) = (idx_ & 15) << 7;                                      \
    (bc) = (xcd_ * 26 + (idx_ >> 4)) << 7;                        \
    (ga) = (const char*)cn8 + (size_t)((br) + srow) * RS + scb;   \
    (gb) = (const char*)hn8 + (size_t)((bc) + srow) * RS + scb;   \
  } while (0)

  // A rows 0..63 at +0, 64..127 at +4096; B likewise at +8192/+12288.
#define STAGE(sb, ga, gb, t) do {                                 \
    char* d_ = ldst + (sb);                                       \
    const char* a_ = (ga) + (t) * 64;                             \
    llds16(a_,           d_);                                     \
    llds16(a_ + 64 * RS, d_ + 4096);                              \
    const char* b_ = (gb) + (t) * 64;                             \
    llds16(b_,           d_ + 8192);                              \
    llds16(b_ + 64 * RS, d_ + 12288);                             \
  } while (0)

  const char *gA, *gB; int brow, bcol;
  DECODE(blockIdx.x, gA, gB, brow, bcol);
  STAGE(0, gA, gB, 0);                       // first tile's k0

  for (int tile = blockIdx.x; tile < NTILE; tile += GRID) {
    asm volatile("s_waitcnt vmcnt(0)" ::: "memory");   // k0 landed
    BAR;

    const bool hasnext = (tile + GRID) < NTILE;
    const char *gA2 = gA, *gB2 = gB; int brow2 = brow, bcol2 = bcol;

    f32x4 acc[4][4] = {};

    for (int t = 0; t < NT; ++t) {
      if (t + 1 < NT) {
        STAGE(((t + 1) & 1) * 16384, gA, gB, t + 1);
      } else if (hasnext) {
        DECODE(tile + GRID, gA2, gB2, brow2, bcol2);
        STAGE(0, gA2, gB2, 0);               // hides under epilogue
      }

      const char* bb = lds + (t & 1) * 16384;
      i64x2 av[4], bv[4];
#pragma unroll
      for (int i = 0; i < 4; ++i) av[i] = *(const i64x2*)(bb + offA + i * 1024);
#pragma unroll
      for (int i = 0; i < 4; ++i) bv[i] = *(const i64x2*)(bb + offB + i * 1024);

      __builtin_amdgcn_s_setprio(1);
#pragma unroll
      for (int mi = 0; mi < 4; ++mi)
#pragma unroll
        for (int ni = 0; ni < 4; ++ni)
          acc[mi][ni] = __builtin_amdgcn_mfma_f32_16x16x32_fp8_fp8(
              av[mi][0], bv[ni][0], acc[mi][ni], 0, 0, 0);
#pragma unroll
      for (int mi = 0; mi < 4; ++mi)
#pragma unroll
        for (int ni = 0; ni < 4; ++ni)
          acc[mi][ni] = __builtin_amdgcn_mfma_f32_16x16x32_fp8_fp8(
              av[mi][1], bv[ni][1], acc[mi][ni], 0, 0, 0);
      __builtin_amdgcn_s_setprio(0);

      if (t + 1 < NT) {
        asm volatile("s_waitcnt vmcnt(0)" ::: "memory");
        BAR;
      }
    }

    // epilogue: row = brow+wm*64+mi*16+q*4+j, col = bcol+wn*64+ni*16+fr
    const int rowb = brow + wm * 64;
    const int colb = bcol + wn * 64;
#pragma unroll
    for (int mi = 0; mi < 4; ++mi) {
#pragma unroll
      for (int j = 0; j < 4; ++j) {
        const int grow = rowb + mi * 16 + q * 4 + j;
        float v = 0.f;
#pragma unroll
        for (int ni = 0; ni < 4; ++ni) {
          const int gcol = colb + ni * 16 + fr;
          const float a = acc[mi][ni][j];
          if ((unsigned)(gcol - grow * 13) < 13u) alignedD[gcol] = a;  // raw dot
          v += ((gcol & 2047) == grow) ? 0.f : __expf(RTEMP * a);     // masked sum
        }
        v += __shfl_xor(v, 1); v += __shfl_xor(v, 2);
        v += __shfl_xor(v, 4); v += __shfl_xor(v, 8);
        if (fr == 0) atomicAdd(&S_all[grow], v);
      }
    }

    gA = gA2; gB = gB2; brow = brow2; bcol = bcol2;
  }
#undef STAGE
#undef DECODE
}

// ---------------------------------------------------------------------------
// Kernel 3: per row i: loss_i = sum_l [ log(exp(20 d_l) + s_i) - 20 d_l ].
// ---------------------------------------------------------------------------
__global__ __launch_bounds__(256) void k_finalize(
    const float* __restrict__ S_all, const float* __restrict__ alignedD,
    float* __restrict__ out)
{
  const int i = blockIdx.x * 256 + threadIdx.x;
  const int lane = threadIdx.x & 63, wid = threadIdx.x >> 6;
  const float s = S_all[i];
  float accv = 0.f;
#pragma unroll
  for (int l = 0; l < L_; l++) {
    const float d = RTEMP * alignedD[i * L_ + l];
    accv += logf(__expf(d) + s) - d;
  }
#pragma unroll
  for (int m = 1; m < 64; m <<= 1) accv += __shfl_xor(accv, m);
  __shared__ float wsum[4];
  if (lane == 0) wsum[wid] = accv;
  __syncthreads();
  if (threadIdx.x == 0)
    atomicAdd(out, (wsum[0] + wsum[1] + wsum[2] + wsum[3]) * (1.0f / (float)(B_ * L_)));
}

// ---------------------------------------------------------------------------
extern "C" void kernel_launch(void* const* d_in, const int* in_sizes, int n_in,
                              void* d_out, int out_size, void* d_ws, size_t ws_size,
                              hipStream_t stream) {
  const float* cls    = (const float*)d_in[0];
  const float* hidden = (const float*)d_in[1];
  float* out = (float*)d_out;

  // ws: hn8 (20,447,232) | cn8 (1,572,864) | S_all (8,192) | alignedD (106,496)
  char* ws = (char*)d_ws;
  unsigned char* hn8 = (unsigned char*)ws;
  unsigned char* cn8 = (unsigned char*)(ws + (size_t)NROW * RS);
  float* S_all    = (float*)(ws + (size_t)NROW * RS + (size_t)B_ * RS);
  float* alignedD = (float*)(ws + (size_t)NROW * RS + (size_t)B_ * RS + B_ * sizeof(float));

  hipMemsetAsync(S_all, 0, B_ * sizeof(float), stream);
  hipMemsetAsync(out, 0, sizeof(float), stream);

  k_normalize<<<(B_ + NROW) / 4, 256, 0, stream>>>(cls, hidden, cn8, hn8);
  k_gemm<<<GRID, 256, 0, stream>>>(cn8, hn8, S_all, alignedD);
  k_finalize<<<B_ / 256, 256, 0, stream>>>(S_all, alignedD, out);
}